// Round 7
// baseline (499.644 us; speedup 1.0000x reference)
//
#include <hip/hip_runtime.h>

#define H 128

typedef __bf16 bf16x8 __attribute__((ext_vector_type(8)));
typedef float f32x4 __attribute__((ext_vector_type(4)));

__device__ __forceinline__ float fsig(float x) {
  return __builtin_amdgcn_rcpf(1.0f + __expf(-x));
}
__device__ __forceinline__ float ftanh(float x) {
  float ax = fabsf(x), e = __expf(-2.0f * ax);
  float t = (1.0f - e) * __builtin_amdgcn_rcpf(1.0f + e);
  return x < 0.0f ? -t : t;
}
__device__ __forceinline__ uint2 pack4(float a, float b, float c, float d) {
  union { __bf16 h[4]; uint2 u; } r;
  r.h[0] = (__bf16)a; r.h[1] = (__bf16)b; r.h[2] = (__bf16)c; r.h[3] = (__bf16)d;
  return r.u;
}
__device__ __forceinline__ unsigned swz(unsigned row, unsigned colByte, unsigned rowBytes) {
  return (row * rowBytes + colByte) ^ ((row & 7) << 4);
}

// ws fragment layouts (uint4 = one lane's 8 bf16):
//   uf_fmt : frags 0..7   (U_f,  K=128)   uint4[0..2048)
//   wf_fmt : frags 0..7   (W_f,  K=128)   uint4[2048..4096)
//   iou_fmt: frags 0..23  ([W_iou;U_iou], K=256) uint4[4096..16384)
__global__ __launch_bounds__(256)
void prep_weights(const float* __restrict__ W_iou, const float* __restrict__ U_iou,
                  const float* __restrict__ W_f, const float* __restrict__ U_f,
                  uint4* __restrict__ ws)
{
  int item = blockIdx.x * 256 + threadIdx.x;   // [0, 16384)
  float v[8];
  if (item < 2048) {
    int fj = item >> 8, rem = item & 255, ks = rem >> 6, lane = rem & 63;
    int n = fj * 16 + (lane & 15), kb = ks * 32 + (lane >> 4) * 8;
    #pragma unroll
    for (int j = 0; j < 8; j++) v[j] = U_f[(kb + j) * H + n];
  } else if (item < 4096) {
    int i2 = item - 2048;
    int fj = i2 >> 8, rem = i2 & 255, ks = rem >> 6, lane = rem & 63;
    int n = fj * 16 + (lane & 15), kb = ks * 32 + (lane >> 4) * 8;
    #pragma unroll
    for (int j = 0; j < 8; j++) v[j] = W_f[(kb + j) * H + n];
  } else {
    int i2 = item - 4096;
    int fj = i2 >> 9, rem = i2 & 511, ks = rem >> 6, lane = rem & 63;
    int col = (fj >> 3) * 128 + (fj & 7) * 16 + (lane & 15);
    int kb = ks * 32 + (lane >> 4) * 8;
    #pragma unroll
    for (int j = 0; j < 8; j++) {
      int k = kb + j;
      v[j] = (k < 128) ? W_iou[k * 384 + col] : U_iou[(k - 128) * 384 + col];
    }
  }
  union { __bf16 h[8]; uint4 u; } r;
  #pragma unroll
  for (int j = 0; j < 8; j++) r.h[j] = (__bf16)v[j];
  ws[item] = r.u;
}

// ================= shared fused body: 32 parents / 128 children =================
// CH: 128*256 B (children h bf16 swz), XH: 32*512 B ([x|h_tilda] bf16 swz),
// SC: 32*128 f32. Stores masked to ploc < npar. Children/x reads may run past
// npar (valid memory in this tree layout; results discarded).
__device__ __forceinline__ void fused_body(
    const float* __restrict__ x, const __bf16* __restrict__ uf_fmt,
    const __bf16* __restrict__ wf_fmt, const __bf16* __restrict__ iou_fmt,
    const float* __restrict__ b_iou, const float* __restrict__ b_f,
    float* __restrict__ h_glob, float* __restrict__ c_glob,
    int prow0, int crow0, int npar,
    char* CH, char* XH, float* SC)
{
  const int t = threadIdx.x;

  // stage children h (+ h_tilda) and parent x
  #pragma unroll
  for (int i = 0; i < 4; i++) {
    int idx = t + i * 256;
    int p = idx >> 5, k0 = (idx & 31) << 2;
    f32x4 s = {};
    #pragma unroll
    for (int j = 0; j < 4; j++) {
      f32x4 v = *reinterpret_cast<const f32x4*>(&h_glob[(size_t)(crow0 + p * 4 + j) * H + k0]);
      *reinterpret_cast<uint2*>(CH + swz(p * 4 + j, k0 * 2, 256)) = pack4(v.x, v.y, v.z, v.w);
      s += v;
    }
    *reinterpret_cast<uint2*>(XH + swz(p, (128 + k0) * 2, 512)) = pack4(s.x, s.y, s.z, s.w);
  }
  #pragma unroll
  for (int i = 0; i < 4; i++) {
    int idx = t + i * 256;
    int p = idx >> 5, k0 = (idx & 31) << 2;
    f32x4 v = *reinterpret_cast<const f32x4*>(&x[(size_t)(prow0 + p) * H + k0]);
    *reinterpret_cast<uint2*>(XH + swz(p, k0 * 2, 512)) = pack4(v.x, v.y, v.z, v.w);
  }
  __syncthreads();

  const int lane = t & 63, w = t >> 6;
  const int l15 = lane & 15, l4 = lane >> 4;

  // P1: SC = x @ W_f
  {
    f32x4 acc[2][2] = {};
    #pragma unroll
    for (int ks = 0; ks < 4; ks++) {
      bf16x8 a[2], b[2];
      #pragma unroll
      for (int m = 0; m < 2; m++)
        a[m] = *reinterpret_cast<const bf16x8*>(XH + swz(m * 16 + l15, (ks * 32 + l4 * 8) * 2, 512));
      #pragma unroll
      for (int n = 0; n < 2; n++) {
        int nf = 2 * w + n;
        b[n] = *reinterpret_cast<const bf16x8*>(wf_fmt + ((size_t)(nf * 4 + ks) * 64 + lane) * 8);
      }
      #pragma unroll
      for (int m = 0; m < 2; m++)
        #pragma unroll
        for (int n = 0; n < 2; n++)
          acc[m][n] = __builtin_amdgcn_mfma_f32_16x16x32_bf16(a[m], b[n], acc[m][n], 0, 0, 0);
    }
    #pragma unroll
    for (int m = 0; m < 2; m++)
      #pragma unroll
      for (int n = 0; n < 2; n++)
        #pragma unroll
        for (int r = 0; r < 4; r++)
          SC[(m * 16 + l4 * 4 + r) * 128 + (2 * w + n) * 16 + l15] = acc[m][n][r];
  }
  __syncthreads();

  // P2: f = sig(h_child@U_f + SC[parent] + b_f); csum overwrites SC (same thread slot)
  {
    f32x4 acc[2][8] = {};
    #pragma unroll
    for (int ks = 0; ks < 4; ks++) {
      bf16x8 a[2], b[8];
      #pragma unroll
      for (int m = 0; m < 2; m++)
        a[m] = *reinterpret_cast<const bf16x8*>(CH + swz(w * 32 + m * 16 + l15, (ks * 32 + l4 * 8) * 2, 256));
      #pragma unroll
      for (int n = 0; n < 8; n++)
        b[n] = *reinterpret_cast<const bf16x8*>(uf_fmt + ((size_t)(n * 4 + ks) * 64 + lane) * 8);
      #pragma unroll
      for (int m = 0; m < 2; m++)
        #pragma unroll
        for (int n = 0; n < 8; n++)
          acc[m][n] = __builtin_amdgcn_mfma_f32_16x16x32_bf16(a[m], b[n], acc[m][n], 0, 0, 0);
    }
    #pragma unroll
    for (int m = 0; m < 2; m++) {
      int rbase = w * 32 + m * 16 + l4 * 4;
      int ploc = rbase >> 2;
      #pragma unroll
      for (int n = 0; n < 8; n++) {
        int ch = n * 16 + l15;
        float sfx = SC[ploc * 128 + ch] + b_f[ch];
        float cs = 0.0f;
        #pragma unroll
        for (int r = 0; r < 4; r++) {
          float f = fsig(acc[m][n][r] + sfx);
          cs = fmaf(f, c_glob[(size_t)(crow0 + rbase + r) * H + ch], cs);
        }
        SC[ploc * 128 + ch] = cs;        // write-after-read, same thread
      }
    }
  }
  __syncthreads();

  // P3: iou = [x|h_tilda] @ [W_iou;U_iou]; finalize h,c
  {
    f32x4 acc[2][3][2] = {};
    #pragma unroll
    for (int ks = 0; ks < 8; ks++) {
      bf16x8 a[2], b[3][2];
      #pragma unroll
      for (int m = 0; m < 2; m++)
        a[m] = *reinterpret_cast<const bf16x8*>(XH + swz(m * 16 + l15, (ks * 32 + l4 * 8) * 2, 512));
      #pragma unroll
      for (int g = 0; g < 3; g++)
        #pragma unroll
        for (int j = 0; j < 2; j++) {
          int nf = g * 8 + 2 * w + j;
          b[g][j] = *reinterpret_cast<const bf16x8*>(iou_fmt + ((size_t)(nf * 8 + ks) * 64 + lane) * 8);
        }
      #pragma unroll
      for (int m = 0; m < 2; m++)
        #pragma unroll
        for (int g = 0; g < 3; g++)
          #pragma unroll
          for (int j = 0; j < 2; j++)
            acc[m][g][j] = __builtin_amdgcn_mfma_f32_16x16x32_bf16(a[m], b[g][j], acc[m][g][j], 0, 0, 0);
    }
    #pragma unroll
    for (int j = 0; j < 2; j++) {
      int ch = (2 * w + j) * 16 + l15;
      float bi = b_iou[ch], bo = b_iou[H + ch], bu = b_iou[2 * H + ch];
      #pragma unroll
      for (int m = 0; m < 2; m++) {
        #pragma unroll
        for (int r = 0; r < 4; r++) {
          int ploc = m * 16 + l4 * 4 + r;
          if (ploc < npar) {
            float gi = acc[m][0][j][r] + bi;
            float go = acc[m][1][j][r] + bo;
            float gu = acc[m][2][j][r] + bu;
            float cs = SC[ploc * 128 + ch];
            float c = fsig(gi) * ftanh(gu) + cs;
            float h = fsig(go) * ftanh(c);
            size_t o = (size_t)(prow0 + ploc) * H + ch;
            h_glob[o] = h;
            c_glob[o] = c;
          }
        }
      }
    }
  }
}

// ================= fused leaf + level-8 kernel =================
__global__ __launch_bounds__(256)
void leaf_l8(const float* __restrict__ x, const __bf16* __restrict__ uf_fmt,
             const __bf16* __restrict__ wf_fmt, const __bf16* __restrict__ iou_fmt,
             const float* __restrict__ b_iou, const float* __restrict__ b_f,
             float* __restrict__ h_glob, float* __restrict__ c_glob,
             int pstart, int cstart)
{
  __shared__ __align__(16) char CH[128 * 256];   // leaf x staging (16KB region) then children h
  __shared__ __align__(16) char XH[32 * 512];
  __shared__ float SC[32 * 128];
  const int t = threadIdx.x;
  const int p0 = blockIdx.x * 32;
  const int c0 = blockIdx.x * 128;
  const int lane = t & 63, w = t >> 6;
  const int l15 = lane & 15, l4 = lane >> 4;

  // ---- leaf phase: two 64-row subtiles ----
  #pragma unroll 1
  for (int sub = 0; sub < 2; sub++) {
    const int r0 = sub * 64;
    #pragma unroll
    for (int i = 0; i < 8; i++) {
      int idx = t + i * 256;
      int r = idx >> 5, k0 = (idx & 31) << 2;
      f32x4 v = *reinterpret_cast<const f32x4*>(&x[(size_t)(cstart + c0 + r0 + r) * H + k0]);
      *reinterpret_cast<uint2*>(CH + swz(r, k0 * 2, 256)) = pack4(v.x, v.y, v.z, v.w);
    }
    __syncthreads();

    #pragma unroll 1                    // sequential halves: 48 live acc
    for (int j = 0; j < 2; j++) {
      f32x4 acc[4][3] = {};
      #pragma unroll
      for (int ks = 0; ks < 4; ks++) {
        bf16x8 a[4], b[3];
        #pragma unroll
        for (int m = 0; m < 4; m++)
          a[m] = *reinterpret_cast<const bf16x8*>(CH + swz(m * 16 + l15, (ks * 32 + l4 * 8) * 2, 256));
        #pragma unroll
        for (int g = 0; g < 3; g++) {
          int nf = g * 8 + 2 * w + j;
          b[g] = *reinterpret_cast<const bf16x8*>(iou_fmt + ((size_t)(nf * 8 + ks) * 64 + lane) * 8);
        }
        #pragma unroll
        for (int m = 0; m < 4; m++)
          #pragma unroll
          for (int g = 0; g < 3; g++)
            acc[m][g] = __builtin_amdgcn_mfma_f32_16x16x32_bf16(a[m], b[g], acc[m][g], 0, 0, 0);
      }
      int ch = (2 * w + j) * 16 + l15;
      float bi = b_iou[ch], bo = b_iou[H + ch], bu = b_iou[2 * H + ch];
      #pragma unroll
      for (int m = 0; m < 4; m++) {
        int rowb = m * 16 + l4 * 4;
        #pragma unroll
        for (int r = 0; r < 4; r++) {
          size_t o = (size_t)(cstart + c0 + r0 + rowb + r) * H + ch;
          float c = fsig(acc[m][0][r] + bi) * ftanh(acc[m][2][r] + bu);
          float h = fsig(acc[m][1][r] + bo) * ftanh(c);
          h_glob[o] = h;
          c_glob[o] = c;
        }
      }
    }
    __syncthreads();                    // CH reads done before restage/reuse
  }

  // ---- level-8 phase: children h,c re-read (L2-hot, same block just wrote them) ----
  fused_body(x, uf_fmt, wf_fmt, iou_fmt, b_iou, b_f, h_glob, c_glob,
             pstart + p0, cstart + c0, 32, CH, XH, SC);
}

// ================= per-level fused kernel (levels 7..4) =================
__global__ __launch_bounds__(256)
void fused_level(const float* __restrict__ x, const __bf16* __restrict__ uf_fmt,
                 const __bf16* __restrict__ wf_fmt, const __bf16* __restrict__ iou_fmt,
                 const float* __restrict__ b_iou, const float* __restrict__ b_f,
                 float* __restrict__ h_glob, float* __restrict__ c_glob,
                 int pstart, int cstart)
{
  __shared__ __align__(16) char CH[128 * 256];
  __shared__ __align__(16) char XH[32 * 512];
  __shared__ float SC[32 * 128];
  fused_body(x, uf_fmt, wf_fmt, iou_fmt, b_iou, b_f, h_glob, c_glob,
             pstart + blockIdx.x * 32, cstart + blockIdx.x * 128, 32, CH, XH, SC);
}

// ================= single-block kernel for levels 3..0 =================
__global__ __launch_bounds__(256)
void top_kernel(const float* __restrict__ x, const __bf16* __restrict__ uf_fmt,
                const __bf16* __restrict__ wf_fmt, const __bf16* __restrict__ iou_fmt,
                const float* __restrict__ b_iou, const float* __restrict__ b_f,
                float* __restrict__ h_glob, float* __restrict__ c_glob)
{
  __shared__ __align__(16) char CH[128 * 256];
  __shared__ __align__(16) char XH[32 * 512];
  __shared__ float SC[32 * 128];
  const int ps[4] = {21, 5, 1, 0};
  const int cs[4] = {85, 21, 5, 1};
  const int np[4] = {64, 16, 4, 1};
  #pragma unroll 1
  for (int li = 0; li < 4; li++) {
    int ntile = (np[li] + 31) >> 5;
    #pragma unroll 1
    for (int tile = 0; tile < ntile; tile++) {
      int npar = np[li] - tile * 32; if (npar > 32) npar = 32;
      fused_body(x, uf_fmt, wf_fmt, iou_fmt, b_iou, b_f, h_glob, c_glob,
                 ps[li] + tile * 32, cs[li] + tile * 128, npar, CH, XH, SC);
      __syncthreads();
    }
  }
}

extern "C" void kernel_launch(void* const* d_in, const int* in_sizes, int n_in,
                              void* d_out, int out_size, void* d_ws, size_t ws_size,
                              hipStream_t stream)
{
  const float* x     = (const float*)d_in[0];
  const float* W_iou = (const float*)d_in[1];
  const float* U_iou = (const float*)d_in[2];
  const float* b_iou = (const float*)d_in[3];
  const float* W_f   = (const float*)d_in[4];
  const float* U_f   = (const float*)d_in[5];
  const float* b_f   = (const float*)d_in[6];
  const int N = 349525;

  float* h_out = (float*)d_out;
  float* c_out = h_out + (size_t)N * H;

  const __bf16* uf_fmt  = (const __bf16*)d_ws;             // 32 KB
  const __bf16* wf_fmt  = (const __bf16*)d_ws + 16384;     // 32 KB
  const __bf16* iou_fmt = (const __bf16*)d_ws + 32768;     // 192 KB

  int off[11];
  off[0] = 0;
  for (int l = 1; l <= 10; l++) off[l] = off[l - 1] * 4 + 1;

  prep_weights<<<64, 256, 0, stream>>>(W_iou, U_iou, W_f, U_f, (uint4*)d_ws);

  // leaves + level 8 fused: 2048 blocks (32 L8 parents + their 128 leaf children each)
  leaf_l8<<<2048, 256, 0, stream>>>(x, uf_fmt, wf_fmt, iou_fmt, b_iou, b_f,
                                    h_out, c_out, off[8], off[9]);

  // levels 7..4
  for (int l = 7; l >= 4; l--) {
    int n_par = off[l + 1] - off[l];
    fused_level<<<n_par / 32, 256, 0, stream>>>(x, uf_fmt, wf_fmt, iou_fmt, b_iou, b_f,
                                                h_out, c_out, off[l], off[l + 1]);
  }

  // levels 3..0: one block, barrier-chained
  top_kernel<<<1, 256, 0, stream>>>(x, uf_fmt, wf_fmt, iou_fmt, b_iou, b_f, h_out, c_out);
}

// Round 8
// 489.373 us; speedup vs baseline: 1.0210x; 1.0210x over previous
//
#include <hip/hip_runtime.h>

#define H 128

typedef __bf16 bf16x8 __attribute__((ext_vector_type(8)));
typedef float f32x4 __attribute__((ext_vector_type(4)));

__device__ __forceinline__ float fsig(float x) {
  return __builtin_amdgcn_rcpf(1.0f + __expf(-x));
}
__device__ __forceinline__ float ftanh(float x) {
  float ax = fabsf(x), e = __expf(-2.0f * ax);
  float t = (1.0f - e) * __builtin_amdgcn_rcpf(1.0f + e);
  return x < 0.0f ? -t : t;
}
__device__ __forceinline__ uint2 pack4(float a, float b, float c, float d) {
  union { __bf16 h[4]; uint2 u; } r;
  r.h[0] = (__bf16)a; r.h[1] = (__bf16)b; r.h[2] = (__bf16)c; r.h[3] = (__bf16)d;
  return r.u;
}
__device__ __forceinline__ unsigned swz(unsigned row, unsigned colByte, unsigned rowBytes) {
  return (row * rowBytes + colByte) ^ ((row & 7) << 4);
}
// async 16B global->LDS (dest wave-uniform base + lane*16)
__device__ __forceinline__ void gload_lds16(const void* g, void* lds) {
  __builtin_amdgcn_global_load_lds((const __attribute__((address_space(1))) void*)g,
                                   (__attribute__((address_space(3))) void*)lds, 16, 0, 0);
}

// ws layout:
//   [0, 256KB)            weight fragments (uint4 granules)
//     uf_fmt : uint4[0..2048)      (U_f, K=128)
//     wf_fmt : uint4[2048..4096)   (W_f, K=128)
//     iou_fmt: uint4[4096..16384)  ([W_iou;U_iou], K=256)
//   [256KB, 256KB+64MB)   hbf: leaf h bf16, per-L8-block swizzled CH layout (2048 x 32KB)
//   [+64MB, +64MB+16MB)   htws: L8 h_tilda bf16 [65536][128]
__global__ __launch_bounds__(256)
void prep_weights(const float* __restrict__ W_iou, const float* __restrict__ U_iou,
                  const float* __restrict__ W_f, const float* __restrict__ U_f,
                  uint4* __restrict__ ws)
{
  int item = blockIdx.x * 256 + threadIdx.x;   // [0, 16384)
  float v[8];
  if (item < 2048) {
    int fj = item >> 8, rem = item & 255, ks = rem >> 6, lane = rem & 63;
    int n = fj * 16 + (lane & 15), kb = ks * 32 + (lane >> 4) * 8;
    #pragma unroll
    for (int j = 0; j < 8; j++) v[j] = U_f[(kb + j) * H + n];
  } else if (item < 4096) {
    int i2 = item - 2048;
    int fj = i2 >> 8, rem = i2 & 255, ks = rem >> 6, lane = rem & 63;
    int n = fj * 16 + (lane & 15), kb = ks * 32 + (lane >> 4) * 8;
    #pragma unroll
    for (int j = 0; j < 8; j++) v[j] = W_f[(kb + j) * H + n];
  } else {
    int i2 = item - 4096;
    int fj = i2 >> 9, rem = i2 & 511, ks = rem >> 6, lane = rem & 63;
    int col = (fj >> 3) * 128 + (fj & 7) * 16 + (lane & 15);
    int kb = ks * 32 + (lane >> 4) * 8;
    #pragma unroll
    for (int j = 0; j < 8; j++) {
      int k = kb + j;
      v[j] = (k < 128) ? W_iou[k * 384 + col] : U_iou[(k - 128) * 384 + col];
    }
  }
  union { __bf16 h[8]; uint4 u; } r;
  #pragma unroll
  for (int j = 0; j < 8; j++) r.h[j] = (__bf16)v[j];
  ws[item] = r.u;
}

// read one A-frag (8 consecutive k f32 -> bf16x8) from swizzled f32 LDS tile
__device__ __forceinline__ bf16x8 read_a_f32(const char* As, int row, int colB) {
  unsigned x1 = (unsigned)row * 512 + ((unsigned)colB ^ ((row & 7) << 4));
  unsigned x2 = (unsigned)row * 512 + ((unsigned)(colB + 16) ^ ((row & 7) << 4));
  f32x4 va = *reinterpret_cast<const f32x4*>(As + x1);
  f32x4 vb = *reinterpret_cast<const f32x4*>(As + x2);
  union { __bf16 h[8]; bf16x8 v; } u;
  u.h[0] = (__bf16)va.x; u.h[1] = (__bf16)va.y; u.h[2] = (__bf16)va.z; u.h[3] = (__bf16)va.w;
  u.h[4] = (__bf16)vb.x; u.h[5] = (__bf16)vb.y; u.h[6] = (__bf16)vb.z; u.h[7] = (__bf16)vb.w;
  return u.v;
}

// ============ leaf: M=64/block, async f32 staging, two sequential N-halves ============
template<bool WS>
__global__ __launch_bounds__(256)
void leaf6(const float* __restrict__ x, const __bf16* __restrict__ iou_fmt,
           const float* __restrict__ b_iou,
           float* __restrict__ h_glob, float* __restrict__ c_glob,
           __bf16* __restrict__ hbf, __bf16* __restrict__ htws, int leaf_start)
{
  __shared__ __align__(16) char As[64 * 512];   // f32 [64][128] swizzled, 32 KB
  const int t = threadIdx.x;
  const int bid = blockIdx.x;
  const int m0 = leaf_start + bid * 64;
  const int lane = t & 63, w = t >> 6;
  const int l15 = lane & 15, l4 = lane >> 4;

  // async stage: pre-swizzled SOURCE + linear LDS dest (rule #21)
  {
    const char* xb = (const char*)(x + (size_t)m0 * H);
    #pragma unroll
    for (int i = 0; i < 8; i++) {
      int d = w * 8192 + i * 1024 + lane * 16;
      int row = d >> 9, c = d & 511;
      gload_lds16(xb + row * 512 + (c ^ ((row & 7) << 4)), As + w * 8192 + i * 1024);
    }
  }
  __syncthreads();

  #pragma unroll 1                      // sequential halves: 48 live acc
  for (int j = 0; j < 2; j++) {
    f32x4 acc[4][3] = {};
    #pragma unroll
    for (int ks = 0; ks < 4; ks++) {
      bf16x8 a[4], b[3];
      #pragma unroll
      for (int m = 0; m < 4; m++)
        a[m] = read_a_f32(As, m * 16 + l15, ks * 128 + l4 * 32);
      #pragma unroll
      for (int g = 0; g < 3; g++) {
        int nf = g * 8 + 2 * w + j;
        b[g] = *reinterpret_cast<const bf16x8*>(iou_fmt + ((size_t)(nf * 8 + ks) * 64 + lane) * 8);
      }
      #pragma unroll
      for (int m = 0; m < 4; m++)
        #pragma unroll
        for (int g = 0; g < 3; g++)
          acc[m][g] = __builtin_amdgcn_mfma_f32_16x16x32_bf16(a[m], b[g], acc[m][g], 0, 0, 0);
    }

    int ch = (2 * w + j) * 16 + l15;
    float bi = b_iou[ch], bo = b_iou[H + ch], bu = b_iou[2 * H + ch];
    #pragma unroll
    for (int m = 0; m < 4; m++) {
      int rowb = m * 16 + l4 * 4;
      float hsum = 0.0f;
      #pragma unroll
      for (int r = 0; r < 4; r++) {
        size_t o = (size_t)(m0 + rowb + r) * H + ch;
        float c = fsig(acc[m][0][r] + bi) * ftanh(acc[m][2][r] + bu);
        float h = fsig(acc[m][1][r] + bo) * ftanh(c);
        h_glob[o] = h;
        c_glob[o] = c;
        if (WS) {
          int CR = bid * 64 + rowb + r;               // child row in [0, 262144)
          unsigned off = ((unsigned)(CR >> 7)) * 32768u + swz(CR & 127, ch * 2, 256);
          *reinterpret_cast<__bf16*>(reinterpret_cast<char*>(hbf) + off) = (__bf16)h;
          hsum += h;
        }
      }
      if (WS) htws[(size_t)(bid * 16 + m * 4 + l4) * H + ch] = (__bf16)hsum;
    }
  }
}

// ================= fused core (post-staging): P1, P2, P3 =================
__device__ __forceinline__ void fused_core(
    const __bf16* __restrict__ uf_fmt, const __bf16* __restrict__ wf_fmt,
    const __bf16* __restrict__ iou_fmt,
    const float* __restrict__ b_iou, const float* __restrict__ b_f,
    float* __restrict__ h_glob, float* __restrict__ c_glob,
    int prow0, int crow0, int npar,
    char* CH, char* XH, float* SC)
{
  const int t = threadIdx.x;
  const int lane = t & 63, w = t >> 6;
  const int l15 = lane & 15, l4 = lane >> 4;

  // P1: SC = x @ W_f
  {
    f32x4 acc[2][2] = {};
    #pragma unroll
    for (int ks = 0; ks < 4; ks++) {
      bf16x8 a[2], b[2];
      #pragma unroll
      for (int m = 0; m < 2; m++)
        a[m] = *reinterpret_cast<const bf16x8*>(XH + swz(m * 16 + l15, (ks * 32 + l4 * 8) * 2, 512));
      #pragma unroll
      for (int n = 0; n < 2; n++) {
        int nf = 2 * w + n;
        b[n] = *reinterpret_cast<const bf16x8*>(wf_fmt + ((size_t)(nf * 4 + ks) * 64 + lane) * 8);
      }
      #pragma unroll
      for (int m = 0; m < 2; m++)
        #pragma unroll
        for (int n = 0; n < 2; n++)
          acc[m][n] = __builtin_amdgcn_mfma_f32_16x16x32_bf16(a[m], b[n], acc[m][n], 0, 0, 0);
    }
    #pragma unroll
    for (int m = 0; m < 2; m++)
      #pragma unroll
      for (int n = 0; n < 2; n++)
        #pragma unroll
        for (int r = 0; r < 4; r++)
          SC[(m * 16 + l4 * 4 + r) * 128 + (2 * w + n) * 16 + l15] = acc[m][n][r];
  }
  __syncthreads();

  // P2: f = sig(h_child@U_f + SC[parent] + b_f); csum overwrites SC (same thread slot)
  {
    f32x4 acc[2][8] = {};
    #pragma unroll
    for (int ks = 0; ks < 4; ks++) {
      bf16x8 a[2], b[8];
      #pragma unroll
      for (int m = 0; m < 2; m++)
        a[m] = *reinterpret_cast<const bf16x8*>(CH + swz(w * 32 + m * 16 + l15, (ks * 32 + l4 * 8) * 2, 256));
      #pragma unroll
      for (int n = 0; n < 8; n++)
        b[n] = *reinterpret_cast<const bf16x8*>(uf_fmt + ((size_t)(n * 4 + ks) * 64 + lane) * 8);
      #pragma unroll
      for (int m = 0; m < 2; m++)
        #pragma unroll
        for (int n = 0; n < 8; n++)
          acc[m][n] = __builtin_amdgcn_mfma_f32_16x16x32_bf16(a[m], b[n], acc[m][n], 0, 0, 0);
    }
    #pragma unroll
    for (int m = 0; m < 2; m++) {
      int rbase = w * 32 + m * 16 + l4 * 4;
      int ploc = rbase >> 2;
      #pragma unroll
      for (int n = 0; n < 8; n++) {
        int ch = n * 16 + l15;
        float sfx = SC[ploc * 128 + ch] + b_f[ch];
        float cs = 0.0f;
        #pragma unroll
        for (int r = 0; r < 4; r++) {
          float f = fsig(acc[m][n][r] + sfx);
          cs = fmaf(f, c_glob[(size_t)(crow0 + rbase + r) * H + ch], cs);
        }
        SC[ploc * 128 + ch] = cs;        // write-after-read, same thread
      }
    }
  }
  __syncthreads();

  // P3: iou = [x|h_tilda] @ [W_iou;U_iou]; finalize h,c
  {
    f32x4 acc[2][3][2] = {};
    #pragma unroll
    for (int ks = 0; ks < 8; ks++) {
      bf16x8 a[2], b[3][2];
      #pragma unroll
      for (int m = 0; m < 2; m++)
        a[m] = *reinterpret_cast<const bf16x8*>(XH + swz(m * 16 + l15, (ks * 32 + l4 * 8) * 2, 512));
      #pragma unroll
      for (int g = 0; g < 3; g++)
        #pragma unroll
        for (int j = 0; j < 2; j++) {
          int nf = g * 8 + 2 * w + j;
          b[g][j] = *reinterpret_cast<const bf16x8*>(iou_fmt + ((size_t)(nf * 8 + ks) * 64 + lane) * 8);
        }
      #pragma unroll
      for (int m = 0; m < 2; m++)
        #pragma unroll
        for (int g = 0; g < 3; g++)
          #pragma unroll
          for (int j = 0; j < 2; j++)
            acc[m][g][j] = __builtin_amdgcn_mfma_f32_16x16x32_bf16(a[m], b[g][j], acc[m][g][j], 0, 0, 0);
    }
    #pragma unroll
    for (int j = 0; j < 2; j++) {
      int ch = (2 * w + j) * 16 + l15;
      float bi = b_iou[ch], bo = b_iou[H + ch], bu = b_iou[2 * H + ch];
      #pragma unroll
      for (int m = 0; m < 2; m++) {
        #pragma unroll
        for (int r = 0; r < 4; r++) {
          int ploc = m * 16 + l4 * 4 + r;
          if (ploc < npar) {
            float gi = acc[m][0][j][r] + bi;
            float go = acc[m][1][j][r] + bo;
            float gu = acc[m][2][j][r] + bu;
            float cs = SC[ploc * 128 + ch];
            float c = fsig(gi) * ftanh(gu) + cs;
            float h = fsig(go) * ftanh(c);
            size_t o = (size_t)(prow0 + ploc) * H + ch;
            h_glob[o] = h;
            c_glob[o] = c;
          }
        }
      }
    }
  }
}

// stage from global f32 h (levels 7..4 and top) then run core
__device__ __forceinline__ void fused_body(
    const float* __restrict__ x, const __bf16* __restrict__ uf_fmt,
    const __bf16* __restrict__ wf_fmt, const __bf16* __restrict__ iou_fmt,
    const float* __restrict__ b_iou, const float* __restrict__ b_f,
    float* __restrict__ h_glob, float* __restrict__ c_glob,
    int prow0, int crow0, int npar,
    char* CH, char* XH, float* SC)
{
  const int t = threadIdx.x;
  #pragma unroll
  for (int i = 0; i < 4; i++) {
    int idx = t + i * 256;
    int p = idx >> 5, k0 = (idx & 31) << 2;
    f32x4 s = {};
    #pragma unroll
    for (int j = 0; j < 4; j++) {
      f32x4 v = *reinterpret_cast<const f32x4*>(&h_glob[(size_t)(crow0 + p * 4 + j) * H + k0]);
      *reinterpret_cast<uint2*>(CH + swz(p * 4 + j, k0 * 2, 256)) = pack4(v.x, v.y, v.z, v.w);
      s += v;
    }
    *reinterpret_cast<uint2*>(XH + swz(p, (128 + k0) * 2, 512)) = pack4(s.x, s.y, s.z, s.w);
  }
  #pragma unroll
  for (int i = 0; i < 4; i++) {
    int idx = t + i * 256;
    int p = idx >> 5, k0 = (idx & 31) << 2;
    f32x4 v = *reinterpret_cast<const f32x4*>(&x[(size_t)(prow0 + p) * H + k0]);
    *reinterpret_cast<uint2*>(XH + swz(p, k0 * 2, 512)) = pack4(v.x, v.y, v.z, v.w);
  }
  __syncthreads();
  fused_core(uf_fmt, wf_fmt, iou_fmt, b_iou, b_f, h_glob, c_glob,
             prow0, crow0, npar, CH, XH, SC);
}

// ================= level-8 kernel: stage from ws (hbf/htws) =================
__global__ __launch_bounds__(256)
void fused_level_ws(const float* __restrict__ x, const __bf16* __restrict__ uf_fmt,
                    const __bf16* __restrict__ wf_fmt, const __bf16* __restrict__ iou_fmt,
                    const float* __restrict__ b_iou, const float* __restrict__ b_f,
                    float* __restrict__ h_glob, float* __restrict__ c_glob,
                    const __bf16* __restrict__ hbf, const __bf16* __restrict__ htws,
                    int pstart, int cstart)
{
  __shared__ __align__(16) char CH[128 * 256];
  __shared__ __align__(16) char XH[32 * 512];
  __shared__ float SC[32 * 128];
  const int t = threadIdx.x;
  const int bid = blockIdx.x;
  const int lane = t & 63, w = t >> 6;

  // CH: linear async copy (content pre-swizzled by leaf6)
  {
    const char* src = reinterpret_cast<const char*>(hbf) + (size_t)bid * 32768;
    #pragma unroll
    for (int i = 0; i < 8; i++) {
      int o = w * 8192 + i * 1024;
      gload_lds16(src + o + lane * 16, CH + o);
    }
  }
  // XH x-half: f32 -> bf16 pack
  #pragma unroll
  for (int i = 0; i < 4; i++) {
    int idx = t + i * 256;
    int p = idx >> 5, k0 = (idx & 31) << 2;
    f32x4 v = *reinterpret_cast<const f32x4*>(&x[(size_t)(pstart + bid * 32 + p) * H + k0]);
    *reinterpret_cast<uint2*>(XH + swz(p, k0 * 2, 512)) = pack4(v.x, v.y, v.z, v.w);
  }
  // XH ht-half: copy from htws
  #pragma unroll
  for (int i = 0; i < 2; i++) {
    int q = t * 2 + i;                  // 16B chunks, 512 total
    int p = q >> 4, cb = (q & 15) * 16;
    uint4 v = *reinterpret_cast<const uint4*>(
        reinterpret_cast<const char*>(htws) + (size_t)(bid * 32 + p) * 256 + cb);
    *reinterpret_cast<uint4*>(XH + p * 512 + ((256 + cb) ^ ((p & 7) << 4))) = v;
  }
  __syncthreads();

  fused_core(uf_fmt, wf_fmt, iou_fmt, b_iou, b_f, h_glob, c_glob,
             pstart + bid * 32, cstart + bid * 128, 32, CH, XH, SC);
}

// ================= per-level fused kernel (levels 7..4, no-ws L8 fallback) =================
__global__ __launch_bounds__(256)
void fused_level(const float* __restrict__ x, const __bf16* __restrict__ uf_fmt,
                 const __bf16* __restrict__ wf_fmt, const __bf16* __restrict__ iou_fmt,
                 const float* __restrict__ b_iou, const float* __restrict__ b_f,
                 float* __restrict__ h_glob, float* __restrict__ c_glob,
                 int pstart, int cstart)
{
  __shared__ __align__(16) char CH[128 * 256];
  __shared__ __align__(16) char XH[32 * 512];
  __shared__ float SC[32 * 128];
  fused_body(x, uf_fmt, wf_fmt, iou_fmt, b_iou, b_f, h_glob, c_glob,
             pstart + blockIdx.x * 32, cstart + blockIdx.x * 128, 32, CH, XH, SC);
}

// ================= single-block kernel for levels 3..0 =================
__global__ __launch_bounds__(256)
void top_kernel(const float* __restrict__ x, const __bf16* __restrict__ uf_fmt,
                const __bf16* __restrict__ wf_fmt, const __bf16* __restrict__ iou_fmt,
                const float* __restrict__ b_iou, const float* __restrict__ b_f,
                float* __restrict__ h_glob, float* __restrict__ c_glob)
{
  __shared__ __align__(16) char CH[128 * 256];
  __shared__ __align__(16) char XH[32 * 512];
  __shared__ float SC[32 * 128];
  const int ps[4] = {21, 5, 1, 0};
  const int cs[4] = {85, 21, 5, 1};
  const int np[4] = {64, 16, 4, 1};
  #pragma unroll 1
  for (int li = 0; li < 4; li++) {
    int ntile = (np[li] + 31) >> 5;
    #pragma unroll 1
    for (int tile = 0; tile < ntile; tile++) {
      int npar = np[li] - tile * 32; if (npar > 32) npar = 32;
      fused_body(x, uf_fmt, wf_fmt, iou_fmt, b_iou, b_f, h_glob, c_glob,
                 ps[li] + tile * 32, cs[li] + tile * 128, npar, CH, XH, SC);
      __syncthreads();
    }
  }
}

extern "C" void kernel_launch(void* const* d_in, const int* in_sizes, int n_in,
                              void* d_out, int out_size, void* d_ws, size_t ws_size,
                              hipStream_t stream)
{
  const float* x     = (const float*)d_in[0];
  const float* W_iou = (const float*)d_in[1];
  const float* U_iou = (const float*)d_in[2];
  const float* b_iou = (const float*)d_in[3];
  const float* W_f   = (const float*)d_in[4];
  const float* U_f   = (const float*)d_in[5];
  const float* b_f   = (const float*)d_in[6];
  const int N = 349525;

  float* h_out = (float*)d_out;
  float* c_out = h_out + (size_t)N * H;

  const __bf16* uf_fmt  = (const __bf16*)d_ws;             // 32 KB
  const __bf16* wf_fmt  = (const __bf16*)d_ws + 16384;     // 32 KB
  const __bf16* iou_fmt = (const __bf16*)d_ws + 32768;     // 192 KB
  __bf16* hbf  = (__bf16*)((char*)d_ws + 262144);          // 64 MB
  __bf16* htws = (__bf16*)((char*)d_ws + 262144 + 67108864); // 16 MB

  const bool use_ws = ws_size >= (262144ULL + 67108864ULL + 16777216ULL);

  int off[11];
  off[0] = 0;
  for (int l = 1; l <= 10; l++) off[l] = off[l - 1] * 4 + 1;

  prep_weights<<<64, 256, 0, stream>>>(W_iou, U_iou, W_f, U_f, (uint4*)d_ws);

  if (use_ws) {
    leaf6<true><<<4096, 256, 0, stream>>>(x, iou_fmt, b_iou, h_out, c_out, hbf, htws, off[9]);
    fused_level_ws<<<2048, 256, 0, stream>>>(x, uf_fmt, wf_fmt, iou_fmt, b_iou, b_f,
                                             h_out, c_out, hbf, htws, off[8], off[9]);
  } else {
    leaf6<false><<<4096, 256, 0, stream>>>(x, iou_fmt, b_iou, h_out, c_out, nullptr, nullptr, off[9]);
    fused_level<<<2048, 256, 0, stream>>>(x, uf_fmt, wf_fmt, iou_fmt, b_iou, b_f,
                                          h_out, c_out, off[8], off[9]);
  }

  // levels 7..4
  for (int l = 7; l >= 4; l--) {
    int n_par = off[l + 1] - off[l];
    fused_level<<<n_par / 32, 256, 0, stream>>>(x, uf_fmt, wf_fmt, iou_fmt, b_iou, b_f,
                                                h_out, c_out, off[l], off[l + 1]);
  }

  // levels 3..0: one block, barrier-chained
  top_kernel<<<1, 256, 0, stream>>>(x, uf_fmt, wf_fmt, iou_fmt, b_iou, b_f, h_out, c_out);
}

// Round 9
// 402.342 us; speedup vs baseline: 1.2418x; 1.2163x over previous
//
#include <hip/hip_runtime.h>

#define H 128

typedef __bf16 bf16x8 __attribute__((ext_vector_type(8)));
typedef float f32x4 __attribute__((ext_vector_type(4)));

__device__ __forceinline__ float fsig(float x) {
  return __builtin_amdgcn_rcpf(1.0f + __expf(-x));
}
__device__ __forceinline__ float ftanh(float x) {
  float ax = fabsf(x), e = __expf(-2.0f * ax);
  float t = (1.0f - e) * __builtin_amdgcn_rcpf(1.0f + e);
  return x < 0.0f ? -t : t;
}
__device__ __forceinline__ uint2 pack4(float a, float b, float c, float d) {
  union { __bf16 h[4]; uint2 u; } r;
  r.h[0] = (__bf16)a; r.h[1] = (__bf16)b; r.h[2] = (__bf16)c; r.h[3] = (__bf16)d;
  return r.u;
}
__device__ __forceinline__ unsigned swz(unsigned row, unsigned colByte, unsigned rowBytes) {
  return (row * rowBytes + colByte) ^ ((row & 7) << 4);
}
// async 16B global->LDS (dest wave-uniform base + lane*16)
__device__ __forceinline__ void gload_lds16(const void* g, void* lds) {
  __builtin_amdgcn_global_load_lds((const __attribute__((address_space(1))) void*)g,
                                   (__attribute__((address_space(3))) void*)lds, 16, 0, 0);
}

// ws layout:
//   [0, 256KB)            weight fragments (uint4 granules)
//     uf_fmt : uint4[0..2048)      (U_f, K=128)
//     wf_fmt : uint4[2048..4096)   (W_f, K=128)
//     iou_fmt: uint4[4096..16384)  ([W_iou;U_iou], K=256)
//   [256KB, 256KB+64MB)   hbf: leaf h bf16, per-L8-block swizzled CH layout (2048 x 32KB)
//   [+64MB, +64MB+16MB)   htws: L8 h_tilda bf16 [65536][128]
__global__ __launch_bounds__(256)
void prep_weights(const float* __restrict__ W_iou, const float* __restrict__ U_iou,
                  const float* __restrict__ W_f, const float* __restrict__ U_f,
                  uint4* __restrict__ ws)
{
  int item = blockIdx.x * 256 + threadIdx.x;   // [0, 16384)
  float v[8];
  if (item < 2048) {
    int fj = item >> 8, rem = item & 255, ks = rem >> 6, lane = rem & 63;
    int n = fj * 16 + (lane & 15), kb = ks * 32 + (lane >> 4) * 8;
    #pragma unroll
    for (int j = 0; j < 8; j++) v[j] = U_f[(kb + j) * H + n];
  } else if (item < 4096) {
    int i2 = item - 2048;
    int fj = i2 >> 8, rem = i2 & 255, ks = rem >> 6, lane = rem & 63;
    int n = fj * 16 + (lane & 15), kb = ks * 32 + (lane >> 4) * 8;
    #pragma unroll
    for (int j = 0; j < 8; j++) v[j] = W_f[(kb + j) * H + n];
  } else {
    int i2 = item - 4096;
    int fj = i2 >> 9, rem = i2 & 511, ks = rem >> 6, lane = rem & 63;
    int col = (fj >> 3) * 128 + (fj & 7) * 16 + (lane & 15);
    int kb = ks * 32 + (lane >> 4) * 8;
    #pragma unroll
    for (int j = 0; j < 8; j++) {
      int k = kb + j;
      v[j] = (k < 128) ? W_iou[k * 384 + col] : U_iou[(k - 128) * 384 + col];
    }
  }
  union { __bf16 h[8]; uint4 u; } r;
  #pragma unroll
  for (int j = 0; j < 8; j++) r.h[j] = (__bf16)v[j];
  ws[item] = r.u;
}

// read one A-frag (8 consecutive k f32 -> bf16x8) from swizzled f32 LDS tile
__device__ __forceinline__ bf16x8 read_a_f32(const char* As, int row, int colB) {
  unsigned x1 = (unsigned)row * 512 + ((unsigned)colB ^ ((row & 7) << 4));
  unsigned x2 = (unsigned)row * 512 + ((unsigned)(colB + 16) ^ ((row & 7) << 4));
  f32x4 va = *reinterpret_cast<const f32x4*>(As + x1);
  f32x4 vb = *reinterpret_cast<const f32x4*>(As + x2);
  union { __bf16 h[8]; bf16x8 v; } u;
  u.h[0] = (__bf16)va.x; u.h[1] = (__bf16)va.y; u.h[2] = (__bf16)va.z; u.h[3] = (__bf16)va.w;
  u.h[4] = (__bf16)vb.x; u.h[5] = (__bf16)vb.y; u.h[6] = (__bf16)vb.z; u.h[7] = (__bf16)vb.w;
  return u.v;
}

// ============ leaf: M=64/block, async f32 staging, two sequential N-halves ============
template<bool WS>
__global__ __launch_bounds__(256)
void leaf6(const float* __restrict__ x, const __bf16* __restrict__ iou_fmt,
           const float* __restrict__ b_iou,
           float* __restrict__ h_glob, float* __restrict__ c_glob,
           __bf16* __restrict__ hbf, __bf16* __restrict__ htws, int leaf_start)
{
  __shared__ __align__(16) char As[64 * 512];   // f32 [64][128] swizzled, 32 KB
  const int t = threadIdx.x;
  const int bid = blockIdx.x;
  const int m0 = leaf_start + bid * 64;
  const int lane = t & 63, w = t >> 6;
  const int l15 = lane & 15, l4 = lane >> 4;

  // async stage: pre-swizzled SOURCE + linear LDS dest (rule #21)
  {
    const char* xb = (const char*)(x + (size_t)m0 * H);
    #pragma unroll
    for (int i = 0; i < 8; i++) {
      int d = w * 8192 + i * 1024 + lane * 16;
      int row = d >> 9, c = d & 511;
      gload_lds16(xb + row * 512 + (c ^ ((row & 7) << 4)), As + w * 8192 + i * 1024);
    }
  }
  __syncthreads();

  #pragma unroll 1                      // sequential halves: 48 live acc
  for (int j = 0; j < 2; j++) {
    f32x4 acc[4][3] = {};
    #pragma unroll
    for (int ks = 0; ks < 4; ks++) {
      bf16x8 a[4], b[3];
      #pragma unroll
      for (int m = 0; m < 4; m++)
        a[m] = read_a_f32(As, m * 16 + l15, ks * 128 + l4 * 32);
      #pragma unroll
      for (int g = 0; g < 3; g++) {
        int nf = g * 8 + 2 * w + j;
        b[g] = *reinterpret_cast<const bf16x8*>(iou_fmt + ((size_t)(nf * 8 + ks) * 64 + lane) * 8);
      }
      #pragma unroll
      for (int m = 0; m < 4; m++)
        #pragma unroll
        for (int g = 0; g < 3; g++)
          acc[m][g] = __builtin_amdgcn_mfma_f32_16x16x32_bf16(a[m], b[g], acc[m][g], 0, 0, 0);
    }

    int ch = (2 * w + j) * 16 + l15;
    float bi = b_iou[ch], bo = b_iou[H + ch], bu = b_iou[2 * H + ch];
    #pragma unroll
    for (int m = 0; m < 4; m++) {
      int rowb = m * 16 + l4 * 4;
      float hsum = 0.0f;
      #pragma unroll
      for (int r = 0; r < 4; r++) {
        size_t o = (size_t)(m0 + rowb + r) * H + ch;
        float c = fsig(acc[m][0][r] + bi) * ftanh(acc[m][2][r] + bu);
        float h = fsig(acc[m][1][r] + bo) * ftanh(c);
        h_glob[o] = h;
        c_glob[o] = c;
        if (WS) {
          int CR = bid * 64 + rowb + r;               // child row in [0, 262144)
          unsigned off = ((unsigned)(CR >> 7)) * 32768u + swz(CR & 127, ch * 2, 256);
          *reinterpret_cast<__bf16*>(reinterpret_cast<char*>(hbf) + off) = (__bf16)h;
          hsum += h;
        }
      }
      if (WS) htws[(size_t)(bid * 16 + m * 4 + l4) * H + ch] = (__bf16)hsum;
    }
  }
}

// ================= fused core (post-staging): P1, P2, P3 =================
__device__ __forceinline__ void fused_core(
    const __bf16* __restrict__ uf_fmt, const __bf16* __restrict__ wf_fmt,
    const __bf16* __restrict__ iou_fmt,
    const float* __restrict__ b_iou, const float* __restrict__ b_f,
    float* __restrict__ h_glob, float* __restrict__ c_glob,
    int prow0, int crow0, int npar,
    char* CH, char* XH, float* SC)
{
  const int t = threadIdx.x;
  const int lane = t & 63, w = t >> 6;
  const int l15 = lane & 15, l4 = lane >> 4;

  // P1: SC = x @ W_f
  {
    f32x4 acc[2][2] = {};
    #pragma unroll
    for (int ks = 0; ks < 4; ks++) {
      bf16x8 a[2], b[2];
      #pragma unroll
      for (int m = 0; m < 2; m++)
        a[m] = *reinterpret_cast<const bf16x8*>(XH + swz(m * 16 + l15, (ks * 32 + l4 * 8) * 2, 512));
      #pragma unroll
      for (int n = 0; n < 2; n++) {
        int nf = 2 * w + n;
        b[n] = *reinterpret_cast<const bf16x8*>(wf_fmt + ((size_t)(nf * 4 + ks) * 64 + lane) * 8);
      }
      #pragma unroll
      for (int m = 0; m < 2; m++)
        #pragma unroll
        for (int n = 0; n < 2; n++)
          acc[m][n] = __builtin_amdgcn_mfma_f32_16x16x32_bf16(a[m], b[n], acc[m][n], 0, 0, 0);
    }
    #pragma unroll
    for (int m = 0; m < 2; m++)
      #pragma unroll
      for (int n = 0; n < 2; n++)
        #pragma unroll
        for (int r = 0; r < 4; r++)
          SC[(m * 16 + l4 * 4 + r) * 128 + (2 * w + n) * 16 + l15] = acc[m][n][r];
  }
  __syncthreads();

  // P2: f = sig(h_child@U_f + SC[parent] + b_f); csum overwrites SC (same thread slot)
  {
    f32x4 acc[2][8] = {};
    #pragma unroll
    for (int ks = 0; ks < 4; ks++) {
      bf16x8 a[2], b[8];
      #pragma unroll
      for (int m = 0; m < 2; m++)
        a[m] = *reinterpret_cast<const bf16x8*>(CH + swz(w * 32 + m * 16 + l15, (ks * 32 + l4 * 8) * 2, 256));
      #pragma unroll
      for (int n = 0; n < 8; n++)
        b[n] = *reinterpret_cast<const bf16x8*>(uf_fmt + ((size_t)(n * 4 + ks) * 64 + lane) * 8);
      #pragma unroll
      for (int m = 0; m < 2; m++)
        #pragma unroll
        for (int n = 0; n < 8; n++)
          acc[m][n] = __builtin_amdgcn_mfma_f32_16x16x32_bf16(a[m], b[n], acc[m][n], 0, 0, 0);
    }
    #pragma unroll
    for (int m = 0; m < 2; m++) {
      int rbase = w * 32 + m * 16 + l4 * 4;
      int ploc = rbase >> 2;
      #pragma unroll
      for (int n = 0; n < 8; n++) {
        int ch = n * 16 + l15;
        float sfx = SC[ploc * 128 + ch] + b_f[ch];
        float cs = 0.0f;
        #pragma unroll
        for (int r = 0; r < 4; r++) {
          float f = fsig(acc[m][n][r] + sfx);
          cs = fmaf(f, c_glob[(size_t)(crow0 + rbase + r) * H + ch], cs);
        }
        SC[ploc * 128 + ch] = cs;        // write-after-read, same thread
      }
    }
  }
  __syncthreads();

  // P3: iou = [x|h_tilda] @ [W_iou;U_iou]; finalize h,c
  {
    f32x4 acc[2][3][2] = {};
    #pragma unroll
    for (int ks = 0; ks < 8; ks++) {
      bf16x8 a[2], b[3][2];
      #pragma unroll
      for (int m = 0; m < 2; m++)
        a[m] = *reinterpret_cast<const bf16x8*>(XH + swz(m * 16 + l15, (ks * 32 + l4 * 8) * 2, 512));
      #pragma unroll
      for (int g = 0; g < 3; g++)
        #pragma unroll
        for (int j = 0; j < 2; j++) {
          int nf = g * 8 + 2 * w + j;
          b[g][j] = *reinterpret_cast<const bf16x8*>(iou_fmt + ((size_t)(nf * 8 + ks) * 64 + lane) * 8);
        }
      #pragma unroll
      for (int m = 0; m < 2; m++)
        #pragma unroll
        for (int g = 0; g < 3; g++)
          #pragma unroll
          for (int j = 0; j < 2; j++)
            acc[m][g][j] = __builtin_amdgcn_mfma_f32_16x16x32_bf16(a[m], b[g][j], acc[m][g][j], 0, 0, 0);
    }
    #pragma unroll
    for (int j = 0; j < 2; j++) {
      int ch = (2 * w + j) * 16 + l15;
      float bi = b_iou[ch], bo = b_iou[H + ch], bu = b_iou[2 * H + ch];
      #pragma unroll
      for (int m = 0; m < 2; m++) {
        #pragma unroll
        for (int r = 0; r < 4; r++) {
          int ploc = m * 16 + l4 * 4 + r;
          if (ploc < npar) {
            float gi = acc[m][0][j][r] + bi;
            float go = acc[m][1][j][r] + bo;
            float gu = acc[m][2][j][r] + bu;
            float cs = SC[ploc * 128 + ch];
            float c = fsig(gi) * ftanh(gu) + cs;
            float h = fsig(go) * ftanh(c);
            size_t o = (size_t)(prow0 + ploc) * H + ch;
            h_glob[o] = h;
            c_glob[o] = c;
          }
        }
      }
    }
  }
}

// stage from global f32 h (levels 7..4) then run core
__device__ __forceinline__ void fused_body(
    const float* __restrict__ x, const __bf16* __restrict__ uf_fmt,
    const __bf16* __restrict__ wf_fmt, const __bf16* __restrict__ iou_fmt,
    const float* __restrict__ b_iou, const float* __restrict__ b_f,
    float* __restrict__ h_glob, float* __restrict__ c_glob,
    int prow0, int crow0, int npar,
    char* CH, char* XH, float* SC)
{
  const int t = threadIdx.x;
  #pragma unroll
  for (int i = 0; i < 4; i++) {
    int idx = t + i * 256;
    int p = idx >> 5, k0 = (idx & 31) << 2;
    f32x4 s = {};
    #pragma unroll
    for (int j = 0; j < 4; j++) {
      f32x4 v = *reinterpret_cast<const f32x4*>(&h_glob[(size_t)(crow0 + p * 4 + j) * H + k0]);
      *reinterpret_cast<uint2*>(CH + swz(p * 4 + j, k0 * 2, 256)) = pack4(v.x, v.y, v.z, v.w);
      s += v;
    }
    *reinterpret_cast<uint2*>(XH + swz(p, (128 + k0) * 2, 512)) = pack4(s.x, s.y, s.z, s.w);
  }
  #pragma unroll
  for (int i = 0; i < 4; i++) {
    int idx = t + i * 256;
    int p = idx >> 5, k0 = (idx & 31) << 2;
    f32x4 v = *reinterpret_cast<const f32x4*>(&x[(size_t)(prow0 + p) * H + k0]);
    *reinterpret_cast<uint2*>(XH + swz(p, k0 * 2, 512)) = pack4(v.x, v.y, v.z, v.w);
  }
  __syncthreads();
  fused_core(uf_fmt, wf_fmt, iou_fmt, b_iou, b_f, h_glob, c_glob,
             prow0, crow0, npar, CH, XH, SC);
}

// ================= level-8 kernel: stage from ws (hbf/htws) =================
__global__ __launch_bounds__(256)
void fused_level_ws(const float* __restrict__ x, const __bf16* __restrict__ uf_fmt,
                    const __bf16* __restrict__ wf_fmt, const __bf16* __restrict__ iou_fmt,
                    const float* __restrict__ b_iou, const float* __restrict__ b_f,
                    float* __restrict__ h_glob, float* __restrict__ c_glob,
                    const __bf16* __restrict__ hbf, const __bf16* __restrict__ htws,
                    int pstart, int cstart)
{
  __shared__ __align__(16) char CH[128 * 256];
  __shared__ __align__(16) char XH[32 * 512];
  __shared__ float SC[32 * 128];
  const int t = threadIdx.x;
  const int bid = blockIdx.x;
  const int lane = t & 63, w = t >> 6;

  // CH: linear async copy (content pre-swizzled by leaf6)
  {
    const char* src = reinterpret_cast<const char*>(hbf) + (size_t)bid * 32768;
    #pragma unroll
    for (int i = 0; i < 8; i++) {
      int o = w * 8192 + i * 1024;
      gload_lds16(src + o + lane * 16, CH + o);
    }
  }
  // XH x-half: f32 -> bf16 pack
  #pragma unroll
  for (int i = 0; i < 4; i++) {
    int idx = t + i * 256;
    int p = idx >> 5, k0 = (idx & 31) << 2;
    f32x4 v = *reinterpret_cast<const f32x4*>(&x[(size_t)(pstart + bid * 32 + p) * H + k0]);
    *reinterpret_cast<uint2*>(XH + swz(p, k0 * 2, 512)) = pack4(v.x, v.y, v.z, v.w);
  }
  // XH ht-half: copy from htws
  #pragma unroll
  for (int i = 0; i < 2; i++) {
    int q = t * 2 + i;                  // 16B chunks, 512 total
    int p = q >> 4, cb = (q & 15) * 16;
    uint4 v = *reinterpret_cast<const uint4*>(
        reinterpret_cast<const char*>(htws) + (size_t)(bid * 32 + p) * 256 + cb);
    *reinterpret_cast<uint4*>(XH + p * 512 + ((256 + cb) ^ ((p & 7) << 4))) = v;
  }
  __syncthreads();

  fused_core(uf_fmt, wf_fmt, iou_fmt, b_iou, b_f, h_glob, c_glob,
             pstart + bid * 32, cstart + bid * 128, 32, CH, XH, SC);
}

// ================= per-level fused kernel (levels 7..4, no-ws L8 fallback) =================
__global__ __launch_bounds__(256)
void fused_level(const float* __restrict__ x, const __bf16* __restrict__ uf_fmt,
                 const __bf16* __restrict__ wf_fmt, const __bf16* __restrict__ iou_fmt,
                 const float* __restrict__ b_iou, const float* __restrict__ b_f,
                 float* __restrict__ h_glob, float* __restrict__ c_glob,
                 int pstart, int cstart)
{
  __shared__ __align__(16) char CH[128 * 256];
  __shared__ __align__(16) char XH[32 * 512];
  __shared__ float SC[32 * 128];
  fused_body(x, uf_fmt, wf_fmt, iou_fmt, b_iou, b_f, h_glob, c_glob,
             pstart + blockIdx.x * 32, cstart + blockIdx.x * 128, 32, CH, XH, SC);
}

// ============ f32 VALU kernel for tiny top levels (3..0): 4 nodes/block ============
#define SNR 4
#define SRP 2
#define BR 4

__global__ __launch_bounds__(256)
void small_kernel(const float* __restrict__ x,
                  const float* __restrict__ W_iou, const float* __restrict__ b_iou,
                  const float* __restrict__ U_iou, const float* __restrict__ W_f,
                  const float* __restrict__ U_f, const float* __restrict__ b_f,
                  float* __restrict__ h_out, float* __restrict__ c_out,
                  int lvl_start, int child_start, int n_lvl)
{
  __shared__ float xs[SNR][H];
  __shared__ float hs[SNR * BR][H];
  __shared__ float ht[SNR][H];
  const int t = threadIdx.x;
  const int node0 = blockIdx.x * SNR;
  const int nrows = min(SNR, n_lvl - node0);

  {
    const f32x4* xgv = reinterpret_cast<const f32x4*>(x + (size_t)(lvl_start + node0) * H);
    f32x4* xsv = reinterpret_cast<f32x4*>(&xs[0][0]);
    int total = nrows * (H / 4);
    for (int i = t; i < total; i += 256) xsv[i] = xgv[i];
  }
  {
    const f32x4* hgv = reinterpret_cast<const f32x4*>(h_out + (size_t)(child_start + node0 * BR) * H);
    f32x4* hsv = reinterpret_cast<f32x4*>(&hs[0][0]);
    int total = nrows * BR * (H / 4);
    for (int i = t; i < total; i += 256) hsv[i] = hgv[i];
  }
  __syncthreads();

  const int ch = t & (H - 1);
  const int g = t >> 7;

  float fx[SRP], ai[SRP], ao[SRP], au[SRP];
  {
    float bi = b_iou[ch], bo = b_iou[ch + H], bu = b_iou[ch + 2 * H], bf = b_f[ch];
    #pragma unroll
    for (int r = 0; r < SRP; r++) { fx[r] = bf; ai[r] = bi; ao[r] = bo; au[r] = bu; }
  }
  {
    const float* wfp = W_f + ch;
    const float* wip = W_iou + ch;
    #pragma unroll 4
    for (int k = 0; k < H; k++) {
      float wf = wfp[k * H];
      float w0 = wip[k * 384], w1 = wip[k * 384 + H], w2 = wip[k * 384 + 2 * H];
      #pragma unroll
      for (int r = 0; r < SRP; r++) {
        float xk = xs[g * SRP + r][k];
        fx[r] = fmaf(xk, wf, fx[r]);
        ai[r] = fmaf(xk, w0, ai[r]);
        ao[r] = fmaf(xk, w1, ao[r]);
        au[r] = fmaf(xk, w2, au[r]);
      }
    }
  }
  #pragma unroll
  for (int r = 0; r < SRP; r++) {
    int row = g * SRP + r;
    float s = hs[row * BR + 0][ch] + hs[row * BR + 1][ch]
            + hs[row * BR + 2][ch] + hs[row * BR + 3][ch];
    ht[row][ch] = s;
  }
  __syncthreads();

  float z[BR][SRP];
  #pragma unroll
  for (int kc = 0; kc < BR; kc++)
    #pragma unroll
    for (int r = 0; r < SRP; r++) z[kc][r] = fx[r];
  {
    const float* ufp = U_f + ch;
    #pragma unroll 4
    for (int m = 0; m < H; m++) {
      float uf = ufp[m * H];
      #pragma unroll
      for (int kc = 0; kc < BR; kc++)
        #pragma unroll
        for (int r = 0; r < SRP; r++)
          z[kc][r] = fmaf(hs[(g * SRP + r) * BR + kc][m], uf, z[kc][r]);
    }
  }
  float csum[SRP];
  #pragma unroll
  for (int r = 0; r < SRP; r++) csum[r] = 0.0f;
  #pragma unroll
  for (int kc = 0; kc < BR; kc++) {
    #pragma unroll
    for (int r = 0; r < SRP; r++) {
      size_t childnode = (size_t)child_start + (size_t)(node0 + g * SRP + r) * BR + kc;
      float f = fsig(z[kc][r]);
      csum[r] = fmaf(f, c_out[childnode * H + ch], csum[r]);
    }
  }
  {
    const float* uip = U_iou + ch;
    #pragma unroll 4
    for (int m = 0; m < H; m++) {
      float w0 = uip[m * 384], w1 = uip[m * 384 + H], w2 = uip[m * 384 + 2 * H];
      #pragma unroll
      for (int r = 0; r < SRP; r++) {
        float hm = ht[g * SRP + r][m];
        ai[r] = fmaf(hm, w0, ai[r]);
        ao[r] = fmaf(hm, w1, ao[r]);
        au[r] = fmaf(hm, w2, au[r]);
      }
    }
  }
  #pragma unroll
  for (int r = 0; r < SRP; r++) {
    int row = g * SRP + r;
    if (row < nrows) {
      float c = fsig(ai[r]) * ftanh(au[r]) + csum[r];
      float h = fsig(ao[r]) * ftanh(c);
      size_t node = (size_t)(lvl_start + node0 + row);
      h_out[node * H + ch] = h;
      c_out[node * H + ch] = c;
    }
  }
}

extern "C" void kernel_launch(void* const* d_in, const int* in_sizes, int n_in,
                              void* d_out, int out_size, void* d_ws, size_t ws_size,
                              hipStream_t stream)
{
  const float* x     = (const float*)d_in[0];
  const float* W_iou = (const float*)d_in[1];
  const float* U_iou = (const float*)d_in[2];
  const float* b_iou = (const float*)d_in[3];
  const float* W_f   = (const float*)d_in[4];
  const float* U_f   = (const float*)d_in[5];
  const float* b_f   = (const float*)d_in[6];
  const int N = 349525;

  float* h_out = (float*)d_out;
  float* c_out = h_out + (size_t)N * H;

  const __bf16* uf_fmt  = (const __bf16*)d_ws;             // 32 KB
  const __bf16* wf_fmt  = (const __bf16*)d_ws + 16384;     // 32 KB
  const __bf16* iou_fmt = (const __bf16*)d_ws + 32768;     // 192 KB
  __bf16* hbf  = (__bf16*)((char*)d_ws + 262144);          // 64 MB
  __bf16* htws = (__bf16*)((char*)d_ws + 262144 + 67108864); // 16 MB

  const bool use_ws = ws_size >= (262144ULL + 67108864ULL + 16777216ULL);

  int off[11];
  off[0] = 0;
  for (int l = 1; l <= 10; l++) off[l] = off[l - 1] * 4 + 1;

  prep_weights<<<64, 256, 0, stream>>>(W_iou, U_iou, W_f, U_f, (uint4*)d_ws);

  if (use_ws) {
    leaf6<true><<<4096, 256, 0, stream>>>(x, iou_fmt, b_iou, h_out, c_out, hbf, htws, off[9]);
    fused_level_ws<<<2048, 256, 0, stream>>>(x, uf_fmt, wf_fmt, iou_fmt, b_iou, b_f,
                                             h_out, c_out, hbf, htws, off[8], off[9]);
  } else {
    leaf6<false><<<4096, 256, 0, stream>>>(x, iou_fmt, b_iou, h_out, c_out, nullptr, nullptr, off[9]);
    fused_level<<<2048, 256, 0, stream>>>(x, uf_fmt, wf_fmt, iou_fmt, b_iou, b_f,
                                          h_out, c_out, off[8], off[9]);
  }

  // levels 7..4
  for (int l = 7; l >= 4; l--) {
    int n_par = off[l + 1] - off[l];
    fused_level<<<n_par / 32, 256, 0, stream>>>(x, uf_fmt, wf_fmt, iou_fmt, b_iou, b_f,
                                                h_out, c_out, off[l], off[l + 1]);
  }

  // levels 3..0: f32 VALU, 4 tiny launches (measured ~25 us total; the
  // single-block MFMA replacement measured 222 us — latency-bound, reverted)
  for (int l = 3; l >= 0; l--) {
    int s = off[l], e = off[l + 1];
    int n = e - s;
    int grid = (n + SNR - 1) / SNR;
    small_kernel<<<grid, 256, 0, stream>>>(x, W_iou, b_iou, U_iou, W_f, U_f, b_f,
                                           h_out, c_out, s, e, n);
  }
}

// Round 10
// 382.664 us; speedup vs baseline: 1.3057x; 1.0514x over previous
//
#include <hip/hip_runtime.h>

#define H 128

typedef __bf16 bf16x8 __attribute__((ext_vector_type(8)));
typedef float f32x4 __attribute__((ext_vector_type(4)));

__device__ __forceinline__ float fsig(float x) {
  return __builtin_amdgcn_rcpf(1.0f + __expf(-x));
}
__device__ __forceinline__ float ftanh(float x) {
  float ax = fabsf(x), e = __expf(-2.0f * ax);
  float t = (1.0f - e) * __builtin_amdgcn_rcpf(1.0f + e);
  return x < 0.0f ? -t : t;
}
__device__ __forceinline__ uint2 pack4(float a, float b, float c, float d) {
  union { __bf16 h[4]; uint2 u; } r;
  r.h[0] = (__bf16)a; r.h[1] = (__bf16)b; r.h[2] = (__bf16)c; r.h[3] = (__bf16)d;
  return r.u;
}
__device__ __forceinline__ unsigned short bfbits(float h) {
  union { __bf16 b; unsigned short u; } cv; cv.b = (__bf16)h; return cv.u;
}
__device__ __forceinline__ unsigned swz(unsigned row, unsigned colByte, unsigned rowBytes) {
  return (row * rowBytes + colByte) ^ ((row & 7) << 4);
}

// ws layout:
//   [0, 256KB)      weight fragments: uf_fmt uint4[0..2048) | wf_fmt [2048..4096) | iou_fmt [4096..16384)
//   [256KB, +64MB)  hb16 leaf region: bf16 [262144][128] row-major (leaf h)
//   [+64MB, +16MB)  hb16 L8 region:   bf16 [65536][128] row-major (level-8 h)
__global__ __launch_bounds__(256)
void prep_weights(const float* __restrict__ W_iou, const float* __restrict__ U_iou,
                  const float* __restrict__ W_f, const float* __restrict__ U_f,
                  uint4* __restrict__ ws)
{
  int item = blockIdx.x * 256 + threadIdx.x;   // [0, 16384)
  float v[8];
  if (item < 2048) {
    int fj = item >> 8, rem = item & 255, ks = rem >> 6, lane = rem & 63;
    int n = fj * 16 + (lane & 15), kb = ks * 32 + (lane >> 4) * 8;
    #pragma unroll
    for (int j = 0; j < 8; j++) v[j] = U_f[(kb + j) * H + n];
  } else if (item < 4096) {
    int i2 = item - 2048;
    int fj = i2 >> 8, rem = i2 & 255, ks = rem >> 6, lane = rem & 63;
    int n = fj * 16 + (lane & 15), kb = ks * 32 + (lane >> 4) * 8;
    #pragma unroll
    for (int j = 0; j < 8; j++) v[j] = W_f[(kb + j) * H + n];
  } else {
    int i2 = item - 4096;
    int fj = i2 >> 9, rem = i2 & 511, ks = rem >> 6, lane = rem & 63;
    int col = (fj >> 3) * 128 + (fj & 7) * 16 + (lane & 15);
    int kb = ks * 32 + (lane >> 4) * 8;
    #pragma unroll
    for (int j = 0; j < 8; j++) {
      int k = kb + j;
      v[j] = (k < 128) ? W_iou[k * 384 + col] : U_iou[(k - 128) * 384 + col];
    }
  }
  union { __bf16 h[8]; uint4 u; } r;
  #pragma unroll
  for (int j = 0; j < 8; j++) r.h[j] = (__bf16)v[j];
  ws[item] = r.u;
}

// one leaf N-half: acc += A(As) @ B(iou_fmt half j)
__device__ __forceinline__ void leaf_half(const char* As, const __bf16* __restrict__ iou_fmt,
                                          int j, int w, int l15, int l4, int lane,
                                          f32x4 (&acc)[4][3])
{
  #pragma unroll
  for (int ks = 0; ks < 4; ks++) {
    bf16x8 a[4], b[3];
    #pragma unroll
    for (int m = 0; m < 4; m++)
      a[m] = *reinterpret_cast<const bf16x8*>(As + swz(m * 16 + l15, (ks * 32 + l4 * 8) * 2, 256));
    #pragma unroll
    for (int g = 0; g < 3; g++) {
      int nf = g * 8 + 2 * w + j;
      b[g] = *reinterpret_cast<const bf16x8*>(iou_fmt + ((size_t)(nf * 8 + ks) * 64 + lane) * 8);
    }
    #pragma unroll
    for (int m = 0; m < 4; m++)
      #pragma unroll
      for (int g = 0; g < 3; g++)
        acc[m][g] = __builtin_amdgcn_mfma_f32_16x16x32_bf16(a[m], b[g], acc[m][g], 0, 0, 0);
  }
}

// ============ leaf: M=64/block, bf16 LDS staging, coalesced bf16-h handoff ============
template<bool WS>
__global__ __launch_bounds__(256)
void leaf8(const float* __restrict__ x, const __bf16* __restrict__ iou_fmt,
           const float* __restrict__ b_iou,
           float* __restrict__ h_glob, float* __restrict__ c_glob,
           __bf16* __restrict__ hb_dst, int leaf_start)
{
  __shared__ __align__(16) char As[64 * 256];   // bf16 [64][128] swz, 16 KB (reused as Hb)
  const int t = threadIdx.x;
  const int bid = blockIdx.x;
  const int m0 = leaf_start + bid * 64;
  const int lane = t & 63, w = t >> 6;
  const int l15 = lane & 15, l4 = lane >> 4;

  #pragma unroll
  for (int i = 0; i < 8; i++) {
    int idx = t + i * 256;
    int r = idx >> 5, k0 = (idx & 31) << 2;
    f32x4 v = *reinterpret_cast<const f32x4*>(&x[(size_t)(m0 + r) * H + k0]);
    *reinterpret_cast<uint2*>(As + swz(r, k0 * 2, 256)) = pack4(v.x, v.y, v.z, v.w);
  }
  __syncthreads();

  unsigned hj0p[8];                      // j=0 h values, bf16-packed (2 per u32)

  // ---- half j=0 ----
  {
    f32x4 acc[4][3] = {};
    leaf_half(As, iou_fmt, 0, w, l15, l4, lane, acc);
    int ch = 2 * w * 16 + l15;
    float bi = b_iou[ch], bo = b_iou[H + ch], bu = b_iou[2 * H + ch];
    #pragma unroll
    for (int m = 0; m < 4; m++) {
      int rowb = m * 16 + l4 * 4;
      unsigned hv[4];
      #pragma unroll
      for (int r = 0; r < 4; r++) {
        size_t o = (size_t)(m0 + rowb + r) * H + ch;
        float c = fsig(acc[m][0][r] + bi) * ftanh(acc[m][2][r] + bu);
        float h = fsig(acc[m][1][r] + bo) * ftanh(c);
        h_glob[o] = h;
        c_glob[o] = c;
        if (WS) hv[r] = bfbits(h);
      }
      if (WS) {
        hj0p[m * 2 + 0] = hv[0] | (hv[1] << 16);
        hj0p[m * 2 + 1] = hv[2] | (hv[3] << 16);
      }
    }
  }

  // ---- half j=1 ----
  {
    f32x4 acc[4][3] = {};
    leaf_half(As, iou_fmt, 1, w, l15, l4, lane, acc);
    __syncthreads();                     // all As reads complete block-wide
    int ch = (2 * w + 1) * 16 + l15;
    float bi = b_iou[ch], bo = b_iou[H + ch], bu = b_iou[2 * H + ch];
    #pragma unroll
    for (int m = 0; m < 4; m++) {
      int rowb = m * 16 + l4 * 4;
      #pragma unroll
      for (int r = 0; r < 4; r++) {
        size_t o = (size_t)(m0 + rowb + r) * H + ch;
        float c = fsig(acc[m][0][r] + bi) * ftanh(acc[m][2][r] + bu);
        float h = fsig(acc[m][1][r] + bo) * ftanh(c);
        h_glob[o] = h;
        c_glob[o] = c;
        if (WS)
          *reinterpret_cast<unsigned short*>(As + swz(rowb + r, ch * 2, 256)) = bfbits(h);
      }
    }
  }

  if (WS) {
    // j=0 h bf16 into Hb (As region)
    int ch0 = 2 * w * 16 + l15;
    #pragma unroll
    for (int m = 0; m < 4; m++) {
      int rowb = m * 16 + l4 * 4;
      #pragma unroll
      for (int r = 0; r < 4; r++) {
        unsigned hv = hj0p[m * 2 + (r >> 1)] >> ((r & 1) * 16);
        *reinterpret_cast<unsigned short*>(As + swz(rowb + r, ch0 * 2, 256)) = (unsigned short)hv;
      }
    }
    __syncthreads();
    // coalesced copy Hb -> hb16 row-major
    char* dst = reinterpret_cast<char*>(hb_dst) + (size_t)bid * 64 * 256;
    #pragma unroll
    for (int i = 0; i < 4; i++) {
      int idx = t + i * 256;
      int row = idx >> 4, chunk = idx & 15;
      uint4 v = *reinterpret_cast<const uint4*>(As + swz(row, chunk * 16, 256));
      *reinterpret_cast<uint4*>(dst + row * 256 + chunk * 16) = v;
    }
  }
}

// ================= fused core (post-staging): P1, P2, P3 =================
// HB: additionally stash parent h as bf16 into CH region (dead after P2)
template<bool HB>
__device__ __forceinline__ void fused_core(
    const __bf16* __restrict__ uf_fmt, const __bf16* __restrict__ wf_fmt,
    const __bf16* __restrict__ iou_fmt,
    const float* __restrict__ b_iou, const float* __restrict__ b_f,
    float* __restrict__ h_glob, float* __restrict__ c_glob,
    int prow0, int crow0, int npar,
    char* CH, char* XH, float* SC)
{
  const int t = threadIdx.x;
  const int lane = t & 63, w = t >> 6;
  const int l15 = lane & 15, l4 = lane >> 4;

  // P1: SC = x @ W_f
  {
    f32x4 acc[2][2] = {};
    #pragma unroll
    for (int ks = 0; ks < 4; ks++) {
      bf16x8 a[2], b[2];
      #pragma unroll
      for (int m = 0; m < 2; m++)
        a[m] = *reinterpret_cast<const bf16x8*>(XH + swz(m * 16 + l15, (ks * 32 + l4 * 8) * 2, 512));
      #pragma unroll
      for (int n = 0; n < 2; n++) {
        int nf = 2 * w + n;
        b[n] = *reinterpret_cast<const bf16x8*>(wf_fmt + ((size_t)(nf * 4 + ks) * 64 + lane) * 8);
      }
      #pragma unroll
      for (int m = 0; m < 2; m++)
        #pragma unroll
        for (int n = 0; n < 2; n++)
          acc[m][n] = __builtin_amdgcn_mfma_f32_16x16x32_bf16(a[m], b[n], acc[m][n], 0, 0, 0);
    }
    #pragma unroll
    for (int m = 0; m < 2; m++)
      #pragma unroll
      for (int n = 0; n < 2; n++)
        #pragma unroll
        for (int r = 0; r < 4; r++)
          SC[(m * 16 + l4 * 4 + r) * 128 + (2 * w + n) * 16 + l15] = acc[m][n][r];
  }
  __syncthreads();

  // P2: f = sig(h_child@U_f + SC[parent] + b_f); csum overwrites SC (same thread slot)
  {
    f32x4 acc[2][8] = {};
    #pragma unroll
    for (int ks = 0; ks < 4; ks++) {
      bf16x8 a[2], b[8];
      #pragma unroll
      for (int m = 0; m < 2; m++)
        a[m] = *reinterpret_cast<const bf16x8*>(CH + swz(w * 32 + m * 16 + l15, (ks * 32 + l4 * 8) * 2, 256));
      #pragma unroll
      for (int n = 0; n < 8; n++)
        b[n] = *reinterpret_cast<const bf16x8*>(uf_fmt + ((size_t)(n * 4 + ks) * 64 + lane) * 8);
      #pragma unroll
      for (int m = 0; m < 2; m++)
        #pragma unroll
        for (int n = 0; n < 8; n++)
          acc[m][n] = __builtin_amdgcn_mfma_f32_16x16x32_bf16(a[m], b[n], acc[m][n], 0, 0, 0);
    }
    #pragma unroll
    for (int m = 0; m < 2; m++) {
      int rbase = w * 32 + m * 16 + l4 * 4;
      int ploc = rbase >> 2;
      #pragma unroll
      for (int n = 0; n < 8; n++) {
        int ch = n * 16 + l15;
        float sfx = SC[ploc * 128 + ch] + b_f[ch];
        float cs = 0.0f;
        #pragma unroll
        for (int r = 0; r < 4; r++) {
          float f = fsig(acc[m][n][r] + sfx);
          cs = fmaf(f, c_glob[(size_t)(crow0 + rbase + r) * H + ch], cs);
        }
        SC[ploc * 128 + ch] = cs;        // write-after-read, same thread
      }
    }
  }
  __syncthreads();

  // P3: iou = [x|h_tilda] @ [W_iou;U_iou]; finalize h,c
  {
    f32x4 acc[2][3][2] = {};
    #pragma unroll
    for (int ks = 0; ks < 8; ks++) {
      bf16x8 a[2], b[3][2];
      #pragma unroll
      for (int m = 0; m < 2; m++)
        a[m] = *reinterpret_cast<const bf16x8*>(XH + swz(m * 16 + l15, (ks * 32 + l4 * 8) * 2, 512));
      #pragma unroll
      for (int g = 0; g < 3; g++)
        #pragma unroll
        for (int j = 0; j < 2; j++) {
          int nf = g * 8 + 2 * w + j;
          b[g][j] = *reinterpret_cast<const bf16x8*>(iou_fmt + ((size_t)(nf * 8 + ks) * 64 + lane) * 8);
        }
      #pragma unroll
      for (int m = 0; m < 2; m++)
        #pragma unroll
        for (int g = 0; g < 3; g++)
          #pragma unroll
          for (int j = 0; j < 2; j++)
            acc[m][g][j] = __builtin_amdgcn_mfma_f32_16x16x32_bf16(a[m], b[g][j], acc[m][g][j], 0, 0, 0);
    }
    #pragma unroll
    for (int j = 0; j < 2; j++) {
      int ch = (2 * w + j) * 16 + l15;
      float bi = b_iou[ch], bo = b_iou[H + ch], bu = b_iou[2 * H + ch];
      #pragma unroll
      for (int m = 0; m < 2; m++) {
        #pragma unroll
        for (int r = 0; r < 4; r++) {
          int ploc = m * 16 + l4 * 4 + r;
          if (ploc < npar) {
            float gi = acc[m][0][j][r] + bi;
            float go = acc[m][1][j][r] + bo;
            float gu = acc[m][2][j][r] + bu;
            float cs = SC[ploc * 128 + ch];
            float c = fsig(gi) * ftanh(gu) + cs;
            float h = fsig(go) * ftanh(c);
            size_t o = (size_t)(prow0 + ploc) * H + ch;
            h_glob[o] = h;
            c_glob[o] = c;
            if (HB)
              *reinterpret_cast<unsigned short*>(CH + swz(ploc, ch * 2, 256)) = bfbits(h);
          }
        }
      }
    }
  }
}

// ================= L8/L7 kernel: stage CH from hb16 (bf16 row-major) =================
template<bool WRITE_HB>
__global__ __launch_bounds__(256)
void fused_hb(const float* __restrict__ x, const __bf16* __restrict__ uf_fmt,
              const __bf16* __restrict__ wf_fmt, const __bf16* __restrict__ iou_fmt,
              const float* __restrict__ b_iou, const float* __restrict__ b_f,
              float* __restrict__ h_glob, float* __restrict__ c_glob,
              const __bf16* __restrict__ ch_src, __bf16* __restrict__ hb_dst,
              int pstart, int cstart)
{
  __shared__ __align__(16) char CH[128 * 256];
  __shared__ __align__(16) char XH[32 * 512];
  __shared__ float SC[32 * 128];
  const int t = threadIdx.x;
  const int bid = blockIdx.x;

  // CH: children h bf16 (row-major ws) -> swizzled LDS, no conversion
  {
    const char* csrc = reinterpret_cast<const char*>(ch_src) + (size_t)bid * 128 * 256;
    #pragma unroll
    for (int i = 0; i < 8; i++) {
      int idx = t + i * 256;
      int row = idx >> 4, chunk = idx & 15;
      uint4 v = *reinterpret_cast<const uint4*>(csrc + row * 256 + chunk * 16);
      *reinterpret_cast<uint4*>(CH + swz(row, chunk * 16, 256)) = v;
    }
  }
  // XH x-half: f32 -> bf16 pack (32 rows)
  #pragma unroll
  for (int i = 0; i < 4; i++) {
    int idx = t + i * 256;
    int p = idx >> 5, k0 = (idx & 31) << 2;
    f32x4 v = *reinterpret_cast<const f32x4*>(&x[(size_t)(pstart + bid * 32 + p) * H + k0]);
    *reinterpret_cast<uint2*>(XH + swz(p, k0 * 2, 512)) = pack4(v.x, v.y, v.z, v.w);
  }
  __syncthreads();
  // XH ht-half: h_tilda = sum of 4 children rows, computed from CH in-LDS
  #pragma unroll
  for (int i = 0; i < 2; i++) {
    int idx = t + i * 256;
    int p = idx >> 4, chunk = idx & 15;
    float s[8] = {};
    #pragma unroll
    for (int cj = 0; cj < 4; cj++) {
      union { uint4 u; __bf16 h[8]; } uv;
      uv.u = *reinterpret_cast<const uint4*>(CH + swz(4 * p + cj, chunk * 16, 256));
      #pragma unroll
      for (int e = 0; e < 8; e++) s[e] += (float)uv.h[e];
    }
    union { __bf16 h[8]; uint4 u; } ov;
    #pragma unroll
    for (int e = 0; e < 8; e++) ov.h[e] = (__bf16)s[e];
    *reinterpret_cast<uint4*>(XH + swz(p, 256 + chunk * 16, 512)) = ov.u;
  }
  __syncthreads();

  fused_core<WRITE_HB>(uf_fmt, wf_fmt, iou_fmt, b_iou, b_f, h_glob, c_glob,
                       pstart + bid * 32, cstart + bid * 128, 32, CH, XH, SC);

  if (WRITE_HB) {
    __syncthreads();
    char* dst = reinterpret_cast<char*>(hb_dst) + (size_t)bid * 32 * 256;
    #pragma unroll
    for (int i = 0; i < 2; i++) {
      int idx = t + i * 256;
      int row = idx >> 4, chunk = idx & 15;
      uint4 v = *reinterpret_cast<const uint4*>(CH + swz(row, chunk * 16, 256));
      *reinterpret_cast<uint4*>(dst + row * 256 + chunk * 16) = v;
    }
  }
}

// classic staging from f32 h (levels 6..4, and L8/L7 fallback)
__device__ __forceinline__ void fused_body(
    const float* __restrict__ x, const __bf16* __restrict__ uf_fmt,
    const __bf16* __restrict__ wf_fmt, const __bf16* __restrict__ iou_fmt,
    const float* __restrict__ b_iou, const float* __restrict__ b_f,
    float* __restrict__ h_glob, float* __restrict__ c_glob,
    int prow0, int crow0, int npar,
    char* CH, char* XH, float* SC)
{
  const int t = threadIdx.x;
  #pragma unroll
  for (int i = 0; i < 4; i++) {
    int idx = t + i * 256;
    int p = idx >> 5, k0 = (idx & 31) << 2;
    f32x4 s = {};
    #pragma unroll
    for (int j = 0; j < 4; j++) {
      f32x4 v = *reinterpret_cast<const f32x4*>(&h_glob[(size_t)(crow0 + p * 4 + j) * H + k0]);
      *reinterpret_cast<uint2*>(CH + swz(p * 4 + j, k0 * 2, 256)) = pack4(v.x, v.y, v.z, v.w);
      s += v;
    }
    *reinterpret_cast<uint2*>(XH + swz(p, (128 + k0) * 2, 512)) = pack4(s.x, s.y, s.z, s.w);
  }
  #pragma unroll
  for (int i = 0; i < 4; i++) {
    int idx = t + i * 256;
    int p = idx >> 5, k0 = (idx & 31) << 2;
    f32x4 v = *reinterpret_cast<const f32x4*>(&x[(size_t)(prow0 + p) * H + k0]);
    *reinterpret_cast<uint2*>(XH + swz(p, k0 * 2, 512)) = pack4(v.x, v.y, v.z, v.w);
  }
  __syncthreads();
  fused_core<false>(uf_fmt, wf_fmt, iou_fmt, b_iou, b_f, h_glob, c_glob,
                    prow0, crow0, npar, CH, XH, SC);
}

__global__ __launch_bounds__(256)
void fused_level(const float* __restrict__ x, const __bf16* __restrict__ uf_fmt,
                 const __bf16* __restrict__ wf_fmt, const __bf16* __restrict__ iou_fmt,
                 const float* __restrict__ b_iou, const float* __restrict__ b_f,
                 float* __restrict__ h_glob, float* __restrict__ c_glob,
                 int pstart, int cstart)
{
  __shared__ __align__(16) char CH[128 * 256];
  __shared__ __align__(16) char XH[32 * 512];
  __shared__ float SC[32 * 128];
  fused_body(x, uf_fmt, wf_fmt, iou_fmt, b_iou, b_f, h_glob, c_glob,
             pstart + blockIdx.x * 32, cstart + blockIdx.x * 128, 32, CH, XH, SC);
}

// ============ f32 VALU kernel for tiny top levels (3..0): 4 nodes/block ============
#define SNR 4
#define SRP 2
#define BR 4

__global__ __launch_bounds__(256)
void small_kernel(const float* __restrict__ x,
                  const float* __restrict__ W_iou, const float* __restrict__ b_iou,
                  const float* __restrict__ U_iou, const float* __restrict__ W_f,
                  const float* __restrict__ U_f, const float* __restrict__ b_f,
                  float* __restrict__ h_out, float* __restrict__ c_out,
                  int lvl_start, int child_start, int n_lvl)
{
  __shared__ float xs[SNR][H];
  __shared__ float hs[SNR * BR][H];
  __shared__ float ht[SNR][H];
  const int t = threadIdx.x;
  const int node0 = blockIdx.x * SNR;
  const int nrows = min(SNR, n_lvl - node0);

  {
    const f32x4* xgv = reinterpret_cast<const f32x4*>(x + (size_t)(lvl_start + node0) * H);
    f32x4* xsv = reinterpret_cast<f32x4*>(&xs[0][0]);
    int total = nrows * (H / 4);
    for (int i = t; i < total; i += 256) xsv[i] = xgv[i];
  }
  {
    const f32x4* hgv = reinterpret_cast<const f32x4*>(h_out + (size_t)(child_start + node0 * BR) * H);
    f32x4* hsv = reinterpret_cast<f32x4*>(&hs[0][0]);
    int total = nrows * BR * (H / 4);
    for (int i = t; i < total; i += 256) hsv[i] = hgv[i];
  }
  __syncthreads();

  const int ch = t & (H - 1);
  const int g = t >> 7;

  float fx[SRP], ai[SRP], ao[SRP], au[SRP];
  {
    float bi = b_iou[ch], bo = b_iou[ch + H], bu = b_iou[ch + 2 * H], bf = b_f[ch];
    #pragma unroll
    for (int r = 0; r < SRP; r++) { fx[r] = bf; ai[r] = bi; ao[r] = bo; au[r] = bu; }
  }
  {
    const float* wfp = W_f + ch;
    const float* wip = W_iou + ch;
    #pragma unroll 4
    for (int k = 0; k < H; k++) {
      float wf = wfp[k * H];
      float w0 = wip[k * 384], w1 = wip[k * 384 + H], w2 = wip[k * 384 + 2 * H];
      #pragma unroll
      for (int r = 0; r < SRP; r++) {
        float xk = xs[g * SRP + r][k];
        fx[r] = fmaf(xk, wf, fx[r]);
        ai[r] = fmaf(xk, w0, ai[r]);
        ao[r] = fmaf(xk, w1, ao[r]);
        au[r] = fmaf(xk, w2, au[r]);
      }
    }
  }
  #pragma unroll
  for (int r = 0; r < SRP; r++) {
    int row = g * SRP + r;
    float s = hs[row * BR + 0][ch] + hs[row * BR + 1][ch]
            + hs[row * BR + 2][ch] + hs[row * BR + 3][ch];
    ht[row][ch] = s;
  }
  __syncthreads();

  float z[BR][SRP];
  #pragma unroll
  for (int kc = 0; kc < BR; kc++)
    #pragma unroll
    for (int r = 0; r < SRP; r++) z[kc][r] = fx[r];
  {
    const float* ufp = U_f + ch;
    #pragma unroll 4
    for (int m = 0; m < H; m++) {
      float uf = ufp[m * H];
      #pragma unroll
      for (int kc = 0; kc < BR; kc++)
        #pragma unroll
        for (int r = 0; r < SRP; r++)
          z[kc][r] = fmaf(hs[(g * SRP + r) * BR + kc][m], uf, z[kc][r]);
    }
  }
  float csum[SRP];
  #pragma unroll
  for (int r = 0; r < SRP; r++) csum[r] = 0.0f;
  #pragma unroll
  for (int kc = 0; kc < BR; kc++) {
    #pragma unroll
    for (int r = 0; r < SRP; r++) {
      size_t childnode = (size_t)child_start + (size_t)(node0 + g * SRP + r) * BR + kc;
      float f = fsig(z[kc][r]);
      csum[r] = fmaf(f, c_out[childnode * H + ch], csum[r]);
    }
  }
  {
    const float* uip = U_iou + ch;
    #pragma unroll 4
    for (int m = 0; m < H; m++) {
      float w0 = uip[m * 384], w1 = uip[m * 384 + H], w2 = uip[m * 384 + 2 * H];
      #pragma unroll
      for (int r = 0; r < SRP; r++) {
        float hm = ht[g * SRP + r][m];
        ai[r] = fmaf(hm, w0, ai[r]);
        ao[r] = fmaf(hm, w1, ao[r]);
        au[r] = fmaf(hm, w2, au[r]);
      }
    }
  }
  #pragma unroll
  for (int r = 0; r < SRP; r++) {
    int row = g * SRP + r;
    if (row < nrows) {
      float c = fsig(ai[r]) * ftanh(au[r]) + csum[r];
      float h = fsig(ao[r]) * ftanh(c);
      size_t node = (size_t)(lvl_start + node0 + row);
      h_out[node * H + ch] = h;
      c_out[node * H + ch] = c;
    }
  }
}

extern "C" void kernel_launch(void* const* d_in, const int* in_sizes, int n_in,
                              void* d_out, int out_size, void* d_ws, size_t ws_size,
                              hipStream_t stream)
{
  const float* x     = (const float*)d_in[0];
  const float* W_iou = (const float*)d_in[1];
  const float* U_iou = (const float*)d_in[2];
  const float* b_iou = (const float*)d_in[3];
  const float* W_f   = (const float*)d_in[4];
  const float* U_f   = (const float*)d_in[5];
  const float* b_f   = (const float*)d_in[6];
  const int N = 349525;

  float* h_out = (float*)d_out;
  float* c_out = h_out + (size_t)N * H;

  const __bf16* uf_fmt  = (const __bf16*)d_ws;             // 32 KB
  const __bf16* wf_fmt  = (const __bf16*)d_ws + 16384;     // 32 KB
  const __bf16* iou_fmt = (const __bf16*)d_ws + 32768;     // 192 KB
  __bf16* hb16 = (__bf16*)((char*)d_ws + 262144);          // leaf 64 MB + L8 16 MB
  __bf16* hb_l8 = hb16 + (size_t)262144 * 128;

  const bool use_ws = ws_size >= (262144ULL + 83886080ULL);

  int off[11];
  off[0] = 0;
  for (int l = 1; l <= 10; l++) off[l] = off[l - 1] * 4 + 1;

  prep_weights<<<64, 256, 0, stream>>>(W_iou, U_iou, W_f, U_f, (uint4*)d_ws);

  if (use_ws) {
    leaf8<true><<<4096, 256, 0, stream>>>(x, iou_fmt, b_iou, h_out, c_out, hb16, off[9]);
    fused_hb<true><<<2048, 256, 0, stream>>>(x, uf_fmt, wf_fmt, iou_fmt, b_iou, b_f,
                                             h_out, c_out, hb16, hb_l8, off[8], off[9]);
    fused_hb<false><<<512, 256, 0, stream>>>(x, uf_fmt, wf_fmt, iou_fmt, b_iou, b_f,
                                             h_out, c_out, hb_l8, nullptr, off[7], off[8]);
  } else {
    leaf8<false><<<4096, 256, 0, stream>>>(x, iou_fmt, b_iou, h_out, c_out, nullptr, off[9]);
    fused_level<<<2048, 256, 0, stream>>>(x, uf_fmt, wf_fmt, iou_fmt, b_iou, b_f,
                                          h_out, c_out, off[8], off[9]);
    fused_level<<<512, 256, 0, stream>>>(x, uf_fmt, wf_fmt, iou_fmt, b_iou, b_f,
                                         h_out, c_out, off[7], off[8]);
  }

  // levels 6..4: classic f32 staging (children are small, LLC-hot)
  for (int l = 6; l >= 4; l--) {
    int n_par = off[l + 1] - off[l];
    fused_level<<<n_par / 32, 256, 0, stream>>>(x, uf_fmt, wf_fmt, iou_fmt, b_iou, b_f,
                                                h_out, c_out, off[l], off[l + 1]);
  }

  // levels 3..0: f32 VALU, tiny launches (measured faster than single-block MFMA)
  for (int l = 3; l >= 0; l--) {
    int s = off[l], e = off[l + 1];
    int n = e - s;
    int grid = (n + SNR - 1) / SNR;
    small_kernel<<<grid, 256, 0, stream>>>(x, W_iou, b_iou, U_iou, W_f, U_f, b_f,
                                           h_out, c_out, s, e, n);
  }
}